// Round 5
// baseline (352.214 us; speedup 1.0000x reference)
//
#include <hip/hip_runtime.h>

#define N_NODES 100000
#define F 128
#define NE 1600000
#define SCAN_CHUNK 512
#define SCAN_BLOCKS ((N_NODES + SCAN_CHUNK - 1) / SCAN_CHUNK)  // 196

// fp32 -> bf16 round-to-nearest-even
__device__ __forceinline__ unsigned short f2bf(float f) {
    unsigned int u = __float_as_uint(f);
    return (unsigned short)((u + 0x7FFFu + ((u >> 16) & 1u)) >> 16);
}
__device__ __forceinline__ float blo(unsigned int v) { return __uint_as_float(v << 16); }
__device__ __forceinline__ float bhi(unsigned int v) { return __uint_as_float(v & 0xFFFF0000u); }

// ---------- Kernel 1: support(bf16) = x @ W. 128 rows/block, w in LDS ----------
__global__ __launch_bounds__(256) void gemm_kernel(const float* __restrict__ x,
                                                   const float* __restrict__ w,
                                                   ushort* __restrict__ sup) {
    __shared__ float ws[F * F];   // 64 KB, row-major [k][c]
    __shared__ float xs[32][F];   // 16 KB
    const int t = threadIdx.x;
#pragma unroll
    for (int i = 0; i < 16; ++i)
        ((float4*)ws)[i * 256 + t] = ((const float4*)w)[i * 256 + t];

    const int cb = t & 31;    // thread owns cols cb*4 .. cb*4+3
    const int rg = t >> 5;    // row group 0..7
    const int rbase = blockIdx.x * 128;

    for (int it = 0; it < 4; ++it) {
        const int r0 = rbase + it * 32;
        __syncthreads();
#pragma unroll
        for (int i = 0; i < 4; ++i) {
            const int idx = i * 256 + t;
            const int rr = idx >> 5;
            const int cc = idx & 31;
            const int gr = r0 + rr;
            float4 v = make_float4(0.f, 0.f, 0.f, 0.f);
            if (gr < N_NODES) v = ((const float4*)x)[(long long)gr * 32 + cc];
            ((float4*)&xs[rr][0])[cc] = v;
        }
        __syncthreads();

        float4 acc[4] = {};
#pragma unroll 4
        for (int k4 = 0; k4 < 32; ++k4) {
            float4 xv[4];
#pragma unroll
            for (int i = 0; i < 4; ++i)
                xv[i] = ((const float4*)&xs[rg * 4 + i][0])[k4];
#pragma unroll
            for (int kk = 0; kk < 4; ++kk) {
                const float4 wv = ((const float4*)&ws[(k4 * 4 + kk) * F])[cb];
#pragma unroll
                for (int i = 0; i < 4; ++i) {
                    const float xk = (kk == 0) ? xv[i].x : (kk == 1) ? xv[i].y
                                   : (kk == 2) ? xv[i].z : xv[i].w;
                    acc[i].x = fmaf(xk, wv.x, acc[i].x);
                    acc[i].y = fmaf(xk, wv.y, acc[i].y);
                    acc[i].z = fmaf(xk, wv.z, acc[i].z);
                    acc[i].w = fmaf(xk, wv.w, acc[i].w);
                }
            }
        }
#pragma unroll
        for (int i = 0; i < 4; ++i) {
            const int r = r0 + rg * 4 + i;
            if (r < N_NODES) {
                ushort4 o;
                o.x = f2bf(acc[i].x); o.y = f2bf(acc[i].y);
                o.z = f2bf(acc[i].z); o.w = f2bf(acc[i].w);
                ((ushort4*)sup)[(long long)r * 32 + cb] = o;
            }
        }
    }
}

// ---------- Kernel 2: histogram of dst ----------
__global__ void hist_kernel(const int* __restrict__ dst, int* __restrict__ deg) {
    const int e = blockIdx.x * blockDim.x + threadIdx.x;
    if (e >= NE) return;
    atomicAdd(&deg[dst[e]], 1);
}

// ---------- Scan kernels ----------
__global__ void scan_partial(const int* __restrict__ deg, int* __restrict__ bsum) {
    __shared__ int red[256];
    const int t = threadIdx.x;
    const int base = blockIdx.x * SCAN_CHUNK;
    int s = 0;
    for (int i = t; i < SCAN_CHUNK; i += 256) {
        const int idx = base + i;
        if (idx < N_NODES) s += deg[idx];
    }
    red[t] = s;
    __syncthreads();
    for (int off = 128; off > 0; off >>= 1) {
        if (t < off) red[t] += red[t + off];
        __syncthreads();
    }
    if (t == 0) bsum[blockIdx.x] = red[0];
}

__global__ void scan_bsum(const int* __restrict__ bsum, int* __restrict__ boff,
                          int* __restrict__ row_ptr) {
    __shared__ int sh[256];
    const int t = threadIdx.x;
    const int v = (t < SCAN_BLOCKS) ? bsum[t] : 0;
    sh[t] = v;
    __syncthreads();
    for (int off = 1; off < 256; off <<= 1) {
        const int u = (t >= off) ? sh[t - off] : 0;
        __syncthreads();
        sh[t] += u;
        __syncthreads();
    }
    if (t < SCAN_BLOCKS) boff[t] = sh[t] - v;
    if (t == 0) row_ptr[N_NODES] = NE;
}

__global__ void scan_apply(const int* __restrict__ deg, const int* __restrict__ boff,
                           int* __restrict__ row_ptr, int* __restrict__ fill) {
    __shared__ int sh[256];
    const int t = threadIdx.x;
    const int base = blockIdx.x * SCAN_CHUNK;
    const int i0 = base + t * 2;
    const int d0 = (i0 < N_NODES) ? deg[i0] : 0;
    const int d1 = (i0 + 1 < N_NODES) ? deg[i0 + 1] : 0;
    const int tsum = d0 + d1;
    sh[t] = tsum;
    __syncthreads();
    for (int off = 1; off < 256; off <<= 1) {
        const int u = (t >= off) ? sh[t - off] : 0;
        __syncthreads();
        sh[t] += u;
        __syncthreads();
    }
    const int texcl = sh[t] - tsum + boff[blockIdx.x];
    if (i0 < N_NODES) { row_ptr[i0] = texcl; fill[i0] = texcl; }
    if (i0 + 1 < N_NODES) { row_ptr[i0 + 1] = texcl + d0; fill[i0 + 1] = texcl + d0; }
}

// ---------- Kernel 4: bucket-fill via atomicExch (4B HBM granule vs 64B for stores) ----------
__global__ void fill_kernel(const int* __restrict__ src,
                            const int* __restrict__ dst,
                            int* __restrict__ fill,
                            int* __restrict__ col) {
    const int e = blockIdx.x * blockDim.x + threadIdx.x;
    if (e >= NE) return;
    const int d = dst[e];
    const int pos = atomicAdd(&fill[d], 1);
    atomicExch(&col[pos], src[e]);
}

// ---------- Kernel 5: gather-aggregate (bf16, dwordx4 gathers, 4 rows/wave-step) ----------
__global__ __launch_bounds__(256) void aggregate_kernel(
    const ushort* __restrict__ sup,
    const int* __restrict__ row_ptr,
    const int* __restrict__ col,
    const float* __restrict__ b,
    float* __restrict__ out) {
    const int wid = threadIdx.x >> 6;
    const int lane = threadIdx.x & 63;
    const int node = blockIdx.x * 4 + wid;
    if (node >= N_NODES) return;

    const int rs = lane >> 4;   // row slot 0..3
    const int fq = lane & 15;   // feature quad: features fq*8 .. fq*8+7

    const int beg = row_ptr[node];
    const int end = row_ptr[node + 1];

    const uint4* sp = (const uint4*)sup;  // row r = uint4 indices r*16 .. r*16+15

    float acc[8] = {};
    for (int base = beg; base < end; base += 64) {
        const int m = min(64, end - base);
        const int mycol = (lane < m) ? col[base + lane] : 0;
        for (int j = 0; j < m; j += 4) {
            const int idx = j + rs;
            const int s = __shfl(mycol, idx < m ? idx : 0);
            if (idx < m) {
                const uint4 v = sp[(long long)s * 16 + fq];
                acc[0] += blo(v.x); acc[1] += bhi(v.x);
                acc[2] += blo(v.y); acc[3] += bhi(v.y);
                acc[4] += blo(v.z); acc[5] += bhi(v.z);
                acc[6] += blo(v.w); acc[7] += bhi(v.w);
            }
        }
    }
    // reduce across the 4 row slots
#pragma unroll
    for (int i = 0; i < 8; ++i) {
        acc[i] += __shfl_xor(acc[i], 16);
        acc[i] += __shfl_xor(acc[i], 32);
    }
    // self-loop contribution (broadcast load, same addr across rs)
    {
        const uint4 v = sp[(long long)node * 16 + fq];
        acc[0] += blo(v.x); acc[1] += bhi(v.x);
        acc[2] += blo(v.y); acc[3] += bhi(v.y);
        acc[4] += blo(v.z); acc[5] += bhi(v.z);
        acc[6] += blo(v.w); acc[7] += bhi(v.w);
    }
    const float inv = 1.0f / (float)(end - beg + 1);
    const float4 b0 = ((const float4*)b)[fq * 2];
    const float4 b1 = ((const float4*)b)[fq * 2 + 1];
    if (rs == 0) {
        float4 r0, r1;
        r0.x = acc[0] * inv + b0.x; r0.y = acc[1] * inv + b0.y;
        r0.z = acc[2] * inv + b0.z; r0.w = acc[3] * inv + b0.w;
        r1.x = acc[4] * inv + b1.x; r1.y = acc[5] * inv + b1.y;
        r1.z = acc[6] * inv + b1.z; r1.w = acc[7] * inv + b1.w;
        float4* o4 = (float4*)out;
        o4[(long long)node * 32 + fq * 2] = r0;
        o4[(long long)node * 32 + fq * 2 + 1] = r1;
    }
}

extern "C" void kernel_launch(void* const* d_in, const int* in_sizes, int n_in,
                              void* d_out, int out_size, void* d_ws, size_t ws_size,
                              hipStream_t stream) {
    const float* x = (const float*)d_in[0];
    const int* src = (const int*)d_in[1];
    const int* dst = (const int*)d_in[2];
    const float* w = (const float*)d_in[3];
    const float* b = (const float*)d_in[4];
    float* out = (float*)d_out;

    char* p = (char*)d_ws;
    ushort* sup = (ushort*)p;    p += ((size_t)N_NODES * F * sizeof(ushort) + 15) & ~15ULL;
    int* deg = (int*)p;          p += ((size_t)N_NODES * sizeof(int) + 15) & ~15ULL;
    int* row_ptr = (int*)p;      p += (((size_t)N_NODES + 1) * sizeof(int) + 15) & ~15ULL;
    int* fill = (int*)p;         p += ((size_t)N_NODES * sizeof(int) + 15) & ~15ULL;
    int* col = (int*)p;          p += ((size_t)NE * sizeof(int) + 15) & ~15ULL;
    int* bsum = (int*)p;         p += ((size_t)SCAN_BLOCKS * sizeof(int) + 15) & ~15ULL;
    int* boff = (int*)p;

    hipMemsetAsync(deg, 0, (size_t)N_NODES * sizeof(int), stream);

    gemm_kernel<<<(N_NODES + 127) / 128, 256, 0, stream>>>(x, w, sup);
    hist_kernel<<<(NE + 255) / 256, 256, 0, stream>>>(dst, deg);
    scan_partial<<<SCAN_BLOCKS, 256, 0, stream>>>(deg, bsum);
    scan_bsum<<<1, 256, 0, stream>>>(bsum, boff, row_ptr);
    scan_apply<<<SCAN_BLOCKS, 256, 0, stream>>>(deg, boff, row_ptr, fill);
    fill_kernel<<<(NE + 255) / 256, 256, 0, stream>>>(src, dst, fill, col);
    aggregate_kernel<<<(N_NODES + 3) / 4, 256, 0, stream>>>(sup, row_ptr, col, b, out);
}

// Round 6
// 204.040 us; speedup vs baseline: 1.7262x; 1.7262x over previous
//
#include <hip/hip_runtime.h>

#define N_NODES 100000
#define F 128
#define NE 1600000
#define NB 256
#define CHUNK (NE / NB)          // 6250
#define NWORDS (N_NODES / 4)     // 25000 packed byte-counters
#define SCAN_CHUNK 512
#define SCAN_BLOCKS ((N_NODES + SCAN_CHUNK - 1) / SCAN_CHUNK)  // 196

// fp32 -> bf16 round-to-nearest-even
__device__ __forceinline__ unsigned short f2bf(float f) {
    unsigned int u = __float_as_uint(f);
    return (unsigned short)((u + 0x7FFFu + ((u >> 16) & 1u)) >> 16);
}
__device__ __forceinline__ float blo(unsigned int v) { return __uint_as_float(v << 16); }
__device__ __forceinline__ float bhi(unsigned int v) { return __uint_as_float(v & 0xFFFF0000u); }

// ---------- Kernel 1: support(bf16) = x @ W. 128 rows/block, w in LDS ----------
__global__ __launch_bounds__(256) void gemm_kernel(const float* __restrict__ x,
                                                   const float* __restrict__ w,
                                                   ushort* __restrict__ sup) {
    __shared__ float ws[F * F];   // 64 KB, row-major [k][c]
    __shared__ float xs[32][F];   // 16 KB
    const int t = threadIdx.x;
#pragma unroll
    for (int i = 0; i < 16; ++i)
        ((float4*)ws)[i * 256 + t] = ((const float4*)w)[i * 256 + t];

    const int cb = t & 31;
    const int rg = t >> 5;
    const int rbase = blockIdx.x * 128;

    for (int it = 0; it < 4; ++it) {
        const int r0 = rbase + it * 32;
        __syncthreads();
#pragma unroll
        for (int i = 0; i < 4; ++i) {
            const int idx = i * 256 + t;
            const int rr = idx >> 5;
            const int cc = idx & 31;
            const int gr = r0 + rr;
            float4 v = make_float4(0.f, 0.f, 0.f, 0.f);
            if (gr < N_NODES) v = ((const float4*)x)[(long long)gr * 32 + cc];
            ((float4*)&xs[rr][0])[cc] = v;
        }
        __syncthreads();

        float4 acc[4] = {};
#pragma unroll 4
        for (int k4 = 0; k4 < 32; ++k4) {
            float4 xv[4];
#pragma unroll
            for (int i = 0; i < 4; ++i)
                xv[i] = ((const float4*)&xs[rg * 4 + i][0])[k4];
#pragma unroll
            for (int kk = 0; kk < 4; ++kk) {
                const float4 wv = ((const float4*)&ws[(k4 * 4 + kk) * F])[cb];
#pragma unroll
                for (int i = 0; i < 4; ++i) {
                    const float xk = (kk == 0) ? xv[i].x : (kk == 1) ? xv[i].y
                                   : (kk == 2) ? xv[i].z : xv[i].w;
                    acc[i].x = fmaf(xk, wv.x, acc[i].x);
                    acc[i].y = fmaf(xk, wv.y, acc[i].y);
                    acc[i].z = fmaf(xk, wv.z, acc[i].z);
                    acc[i].w = fmaf(xk, wv.w, acc[i].w);
                }
            }
        }
#pragma unroll
        for (int i = 0; i < 4; ++i) {
            const int r = r0 + rg * 4 + i;
            if (r < N_NODES) {
                ushort4 o;
                o.x = f2bf(acc[i].x); o.y = f2bf(acc[i].y);
                o.z = f2bf(acc[i].z); o.w = f2bf(acc[i].w);
                ((ushort4*)sup)[(long long)r * 32 + cb] = o;
            }
        }
    }
}

// ---------- Phase A: per-chunk histogram (LDS byte-packed), dump to H[b][N] ----------
__global__ __launch_bounds__(1024) void chunk_hist(const int* __restrict__ dst,
                                                   unsigned char* __restrict__ H) {
    __shared__ unsigned int bins[NWORDS];  // 100 KB: 4 byte-counters per word
    for (int i = threadIdx.x; i < NWORDS; i += 1024) bins[i] = 0;
    __syncthreads();
    const int b = blockIdx.x;
    const int e0 = b * CHUNK;
    for (int i = threadIdx.x; i < CHUNK; i += 1024) {
        const int d = dst[e0 + i];
        atomicAdd(&bins[d >> 2], 1u << ((d & 3) * 8));
    }
    __syncthreads();
    uint4* Ho = (uint4*)(H + (size_t)b * N_NODES);
    const uint4* bi = (const uint4*)bins;
    for (int i = threadIdx.x; i < NWORDS / 4; i += 1024) Ho[i] = bi[i];
}

// ---------- Phase B: in-place exclusive scan of H along chunks; emit deg ----------
__global__ void chunk_scan(unsigned char* __restrict__ H, int* __restrict__ deg) {
    const int d = blockIdx.x * blockDim.x + threadIdx.x;
    if (d >= N_NODES) return;
    int run = 0;
#pragma unroll 8
    for (int b = 0; b < NB; ++b) {
        const size_t idx = (size_t)b * N_NODES + d;
        const int t = H[idx];
        H[idx] = (unsigned char)run;
        run += t;
    }
    deg[d] = run;
}

// ---------- Scan kernels: two-level exclusive scan over deg -> row_ptr ----------
__global__ void scan_partial(const int* __restrict__ deg, int* __restrict__ bsum) {
    __shared__ int red[256];
    const int t = threadIdx.x;
    const int base = blockIdx.x * SCAN_CHUNK;
    int s = 0;
    for (int i = t; i < SCAN_CHUNK; i += 256) {
        const int idx = base + i;
        if (idx < N_NODES) s += deg[idx];
    }
    red[t] = s;
    __syncthreads();
    for (int off = 128; off > 0; off >>= 1) {
        if (t < off) red[t] += red[t + off];
        __syncthreads();
    }
    if (t == 0) bsum[blockIdx.x] = red[0];
}

__global__ void scan_bsum(const int* __restrict__ bsum, int* __restrict__ boff,
                          int* __restrict__ row_ptr) {
    __shared__ int sh[256];
    const int t = threadIdx.x;
    const int v = (t < SCAN_BLOCKS) ? bsum[t] : 0;
    sh[t] = v;
    __syncthreads();
    for (int off = 1; off < 256; off <<= 1) {
        const int u = (t >= off) ? sh[t - off] : 0;
        __syncthreads();
        sh[t] += u;
        __syncthreads();
    }
    if (t < SCAN_BLOCKS) boff[t] = sh[t] - v;
    if (t == 0) row_ptr[N_NODES] = NE;
}

__global__ void scan_apply(const int* __restrict__ deg, const int* __restrict__ boff,
                           int* __restrict__ row_ptr) {
    __shared__ int sh[256];
    const int t = threadIdx.x;
    const int base = blockIdx.x * SCAN_CHUNK;
    const int i0 = base + t * 2;
    const int d0 = (i0 < N_NODES) ? deg[i0] : 0;
    const int d1 = (i0 + 1 < N_NODES) ? deg[i0 + 1] : 0;
    const int tsum = d0 + d1;
    sh[t] = tsum;
    __syncthreads();
    for (int off = 1; off < 256; off <<= 1) {
        const int u = (t >= off) ? sh[t - off] : 0;
        __syncthreads();
        sh[t] += u;
        __syncthreads();
    }
    const int texcl = sh[t] - tsum + boff[blockIdx.x];
    if (i0 < N_NODES) row_ptr[i0] = texcl;
    if (i0 + 1 < N_NODES) row_ptr[i0 + 1] = texcl + d0;
}

// ---------- Phase C: CSR fill, rank via LDS atomics only ----------
__global__ __launch_bounds__(1024) void fill2_kernel(const int* __restrict__ src,
                                                     const int* __restrict__ dst,
                                                     const unsigned char* __restrict__ H,
                                                     const int* __restrict__ row_ptr,
                                                     int* __restrict__ col) {
    __shared__ unsigned int bins[NWORDS];  // 100 KB rank counters
    for (int i = threadIdx.x; i < NWORDS; i += 1024) bins[i] = 0;
    __syncthreads();
    const int b = blockIdx.x;
    const int e0 = b * CHUNK;
    const unsigned char* Hb = H + (size_t)b * N_NODES;
    for (int i = threadIdx.x; i < CHUNK; i += 1024) {
        const int e = e0 + i;
        const int d = dst[e];
        const unsigned int sh = (d & 3) * 8;
        const unsigned int old = atomicAdd(&bins[d >> 2], 1u << sh);
        const int lrank = (old >> sh) & 0xFF;
        const int pos = row_ptr[d] + (int)Hb[d] + lrank;
        col[pos] = src[e];
    }
}

// ---------- Kernel 5: gather-aggregate (bf16, dwordx4 gathers, 4 rows/wave-step) ----------
__global__ __launch_bounds__(256) void aggregate_kernel(
    const ushort* __restrict__ sup,
    const int* __restrict__ row_ptr,
    const int* __restrict__ col,
    const float* __restrict__ b,
    float* __restrict__ out) {
    const int wid = threadIdx.x >> 6;
    const int lane = threadIdx.x & 63;
    const int node = blockIdx.x * 4 + wid;
    if (node >= N_NODES) return;

    const int rs = lane >> 4;   // row slot 0..3
    const int fq = lane & 15;   // feature quad

    const int beg = row_ptr[node];
    const int end = row_ptr[node + 1];

    const uint4* sp = (const uint4*)sup;

    float acc[8] = {};
    for (int base = beg; base < end; base += 64) {
        const int m = min(64, end - base);
        const int mycol = (lane < m) ? col[base + lane] : 0;
        for (int j = 0; j < m; j += 4) {
            const int idx = j + rs;
            const int s = __shfl(mycol, idx < m ? idx : 0);
            if (idx < m) {
                const uint4 v = sp[(long long)s * 16 + fq];
                acc[0] += blo(v.x); acc[1] += bhi(v.x);
                acc[2] += blo(v.y); acc[3] += bhi(v.y);
                acc[4] += blo(v.z); acc[5] += bhi(v.z);
                acc[6] += blo(v.w); acc[7] += bhi(v.w);
            }
        }
    }
#pragma unroll
    for (int i = 0; i < 8; ++i) {
        acc[i] += __shfl_xor(acc[i], 16);
        acc[i] += __shfl_xor(acc[i], 32);
    }
    {
        const uint4 v = sp[(long long)node * 16 + fq];
        acc[0] += blo(v.x); acc[1] += bhi(v.x);
        acc[2] += blo(v.y); acc[3] += bhi(v.y);
        acc[4] += blo(v.z); acc[5] += bhi(v.z);
        acc[6] += blo(v.w); acc[7] += bhi(v.w);
    }
    const float inv = 1.0f / (float)(end - beg + 1);
    const float4 b0 = ((const float4*)b)[fq * 2];
    const float4 b1 = ((const float4*)b)[fq * 2 + 1];
    if (rs == 0) {
        float4 r0, r1;
        r0.x = acc[0] * inv + b0.x; r0.y = acc[1] * inv + b0.y;
        r0.z = acc[2] * inv + b0.z; r0.w = acc[3] * inv + b0.w;
        r1.x = acc[4] * inv + b1.x; r1.y = acc[5] * inv + b1.y;
        r1.z = acc[6] * inv + b1.z; r1.w = acc[7] * inv + b1.w;
        float4* o4 = (float4*)out;
        o4[(long long)node * 32 + fq * 2] = r0;
        o4[(long long)node * 32 + fq * 2 + 1] = r1;
    }
}

extern "C" void kernel_launch(void* const* d_in, const int* in_sizes, int n_in,
                              void* d_out, int out_size, void* d_ws, size_t ws_size,
                              hipStream_t stream) {
    const float* x = (const float*)d_in[0];
    const int* src = (const int*)d_in[1];
    const int* dst = (const int*)d_in[2];
    const float* w = (const float*)d_in[3];
    const float* b = (const float*)d_in[4];
    float* out = (float*)d_out;

    // Workspace: sup 25.6MB | deg .4MB | row_ptr .4MB | col 6.4MB | H 25.6MB | bsum/boff
    char* p = (char*)d_ws;
    ushort* sup = (ushort*)p;    p += ((size_t)N_NODES * F * sizeof(ushort) + 15) & ~15ULL;
    int* deg = (int*)p;          p += ((size_t)N_NODES * sizeof(int) + 15) & ~15ULL;
    int* row_ptr = (int*)p;      p += (((size_t)N_NODES + 1) * sizeof(int) + 15) & ~15ULL;
    int* col = (int*)p;          p += ((size_t)NE * sizeof(int) + 15) & ~15ULL;
    unsigned char* H = (unsigned char*)p;  p += ((size_t)NB * N_NODES + 15) & ~15ULL;
    int* bsum = (int*)p;         p += ((size_t)SCAN_BLOCKS * sizeof(int) + 15) & ~15ULL;
    int* boff = (int*)p;

    gemm_kernel<<<(N_NODES + 127) / 128, 256, 0, stream>>>(x, w, sup);
    chunk_hist<<<NB, 1024, 0, stream>>>(dst, H);
    chunk_scan<<<(N_NODES + 255) / 256, 256, 0, stream>>>(H, deg);
    scan_partial<<<SCAN_BLOCKS, 256, 0, stream>>>(deg, bsum);
    scan_bsum<<<1, 256, 0, stream>>>(bsum, boff, row_ptr);
    scan_apply<<<SCAN_BLOCKS, 256, 0, stream>>>(deg, boff, row_ptr);
    fill2_kernel<<<NB, 1024, 0, stream>>>(src, dst, H, row_ptr, col);
    aggregate_kernel<<<(N_NODES + 3) / 4, 256, 0, stream>>>(sup, row_ptr, col, b, out);
}

// Round 7
// 162.476 us; speedup vs baseline: 2.1678x; 1.2558x over previous
//
#include <hip/hip_runtime.h>

#define N_NODES 100000
#define F 128
#define NE 1600000
#define NB 256
#define CHUNK (NE / NB)          // 6250
#define NWORDS (N_NODES / 4)     // 25000 packed byte-counters
#define SCAN_CHUNK 512
#define SCAN_BLOCKS ((N_NODES + SCAN_CHUNK - 1) / SCAN_CHUNK)  // 196

typedef __attribute__((ext_vector_type(8))) short bf16x8;
typedef __attribute__((ext_vector_type(4))) float f32x4;

// fp32 -> bf16 round-to-nearest-even
__device__ __forceinline__ unsigned short f2bf(float f) {
    unsigned int u = __float_as_uint(f);
    return (unsigned short)((u + 0x7FFFu + ((u >> 16) & 1u)) >> 16);
}
__device__ __forceinline__ float blo(unsigned int v) { return __uint_as_float(v << 16); }
__device__ __forceinline__ float bhi(unsigned int v) { return __uint_as_float(v & 0xFFFF0000u); }

// ---------- Kernel 1: support(bf16) = x @ W via MFMA. 128x128 tile, 4 waves ----------
__global__ __launch_bounds__(256) void gemm_mfma(const float* __restrict__ x,
                                                 const float* __restrict__ w,
                                                 ushort* __restrict__ sup) {
    // XOR-swizzled bf16 tiles: ushort idx = row*128 + (k ^ ((row&15)<<3))
    __shared__ ushort xs[128 * 128];   // 32 KB  [m][k]
    __shared__ ushort wt[128 * 128];   // 32 KB  [n][k]  (W transposed)
    const int t = threadIdx.x;
    const int rbase = blockIdx.x * 128;

    // stage W^T: thread handles column c = f&127, k-quad kq = f>>7
#pragma unroll
    for (int it = 0; it < 16; ++it) {
        const int f = it * 256 + t;
        const int c = f & 127;
        const int kq = f >> 7;          // 0..31, k = 4*kq..+3
        ushort4 o;
        o.x = f2bf(w[(4 * kq + 0) * F + c]);
        o.y = f2bf(w[(4 * kq + 1) * F + c]);
        o.z = f2bf(w[(4 * kq + 2) * F + c]);
        o.w = f2bf(w[(4 * kq + 3) * F + c]);
        ((ushort4*)wt)[c * 32 + (kq ^ ((c & 15) << 1))] = o;
    }
    // stage x tile as bf16: thread handles row r = f>>5, float4 col-group cg = f&31
#pragma unroll
    for (int it = 0; it < 16; ++it) {
        const int f = it * 256 + t;
        const int r = f >> 5;
        const int cg = f & 31;
        const int gr = rbase + r;
        float4 v = make_float4(0.f, 0.f, 0.f, 0.f);
        if (gr < N_NODES) v = ((const float4*)x)[(long long)gr * 32 + cg];
        ushort4 o;
        o.x = f2bf(v.x); o.y = f2bf(v.y); o.z = f2bf(v.z); o.w = f2bf(v.w);
        ((ushort4*)xs)[r * 32 + (cg ^ ((r & 15) << 1))] = o;
    }
    __syncthreads();

    const int wid = t >> 6;
    const int lane = t & 63;
    const int wr = wid >> 1;      // wave row-half
    const int wc = wid & 1;       // wave col-half
    const int l16 = lane & 15;
    const int kg = lane >> 4;     // 0..3

    f32x4 acc[4][4] = {};         // [mi][ni]
    const bf16x8* xs8 = (const bf16x8*)xs;
    const bf16x8* wt8 = (const bf16x8*)wt;

#pragma unroll
    for (int ks = 0; ks < 4; ++ks) {
        const int k8 = ks * 4 + kg;     // k/8
        bf16x8 a[4], bb[4];
#pragma unroll
        for (int mi = 0; mi < 4; ++mi) {
            const int r = wr * 64 + mi * 16 + l16;
            a[mi] = xs8[r * 16 + (k8 ^ (r & 15))];
        }
#pragma unroll
        for (int ni = 0; ni < 4; ++ni) {
            const int c = wc * 64 + ni * 16 + l16;
            bb[ni] = wt8[c * 16 + (k8 ^ (c & 15))];
        }
#pragma unroll
        for (int mi = 0; mi < 4; ++mi)
#pragma unroll
            for (int ni = 0; ni < 4; ++ni)
                acc[mi][ni] = __builtin_amdgcn_mfma_f32_16x16x32_bf16(
                    a[mi], bb[ni], acc[mi][ni], 0, 0, 0);
    }

    // C/D layout: col = lane&15, row = (lane>>4)*4 + reg  [m89-verified]
#pragma unroll
    for (int mi = 0; mi < 4; ++mi) {
#pragma unroll
        for (int reg = 0; reg < 4; ++reg) {
            const int r = rbase + wr * 64 + mi * 16 + kg * 4 + reg;
            if (r < N_NODES) {
#pragma unroll
                for (int ni = 0; ni < 4; ++ni) {
                    const int c = wc * 64 + ni * 16 + l16;
                    sup[(long long)r * F + c] = f2bf(acc[mi][ni][reg]);
                }
            }
        }
    }
}

// ---------- Phase A: per-chunk histogram (LDS byte-packed), dump to H[b][N] ----------
__global__ __launch_bounds__(1024) void chunk_hist(const int* __restrict__ dst,
                                                   unsigned char* __restrict__ H) {
    __shared__ unsigned int bins[NWORDS];  // 100 KB
    for (int i = threadIdx.x; i < NWORDS; i += 1024) bins[i] = 0;
    __syncthreads();
    const int b = blockIdx.x;
    const int e0 = b * CHUNK;
    for (int i = threadIdx.x; i < CHUNK; i += 1024) {
        const int d = dst[e0 + i];
        atomicAdd(&bins[d >> 2], 1u << ((d & 3) * 8));
    }
    __syncthreads();
    uint4* Ho = (uint4*)(H + (size_t)b * N_NODES);
    const uint4* bi = (const uint4*)bins;
    for (int i = threadIdx.x; i < NWORDS / 4; i += 1024) Ho[i] = bi[i];
}

// ---------- Phase B: in-place exclusive scan of H along chunks; emit deg ----------
__global__ void chunk_scan(unsigned char* __restrict__ H, int* __restrict__ deg) {
    const int d = blockIdx.x * blockDim.x + threadIdx.x;
    if (d >= N_NODES) return;
    int run = 0;
#pragma unroll 8
    for (int b = 0; b < NB; ++b) {
        const size_t idx = (size_t)b * N_NODES + d;
        const int t = H[idx];
        H[idx] = (unsigned char)run;
        run += t;
    }
    deg[d] = run;
}

// ---------- Scan kernels: two-level exclusive scan over deg -> row_ptr ----------
__global__ void scan_partial(const int* __restrict__ deg, int* __restrict__ bsum) {
    __shared__ int red[256];
    const int t = threadIdx.x;
    const int base = blockIdx.x * SCAN_CHUNK;
    int s = 0;
    for (int i = t; i < SCAN_CHUNK; i += 256) {
        const int idx = base + i;
        if (idx < N_NODES) s += deg[idx];
    }
    red[t] = s;
    __syncthreads();
    for (int off = 128; off > 0; off >>= 1) {
        if (t < off) red[t] += red[t + off];
        __syncthreads();
    }
    if (t == 0) bsum[blockIdx.x] = red[0];
}

__global__ void scan_bsum(const int* __restrict__ bsum, int* __restrict__ boff,
                          int* __restrict__ row_ptr) {
    __shared__ int sh[256];
    const int t = threadIdx.x;
    const int v = (t < SCAN_BLOCKS) ? bsum[t] : 0;
    sh[t] = v;
    __syncthreads();
    for (int off = 1; off < 256; off <<= 1) {
        const int u = (t >= off) ? sh[t - off] : 0;
        __syncthreads();
        sh[t] += u;
        __syncthreads();
    }
    if (t < SCAN_BLOCKS) boff[t] = sh[t] - v;
    if (t == 0) row_ptr[N_NODES] = NE;
}

__global__ void scan_apply(const int* __restrict__ deg, const int* __restrict__ boff,
                           int* __restrict__ row_ptr) {
    __shared__ int sh[256];
    const int t = threadIdx.x;
    const int base = blockIdx.x * SCAN_CHUNK;
    const int i0 = base + t * 2;
    const int d0 = (i0 < N_NODES) ? deg[i0] : 0;
    const int d1 = (i0 + 1 < N_NODES) ? deg[i0 + 1] : 0;
    const int tsum = d0 + d1;
    sh[t] = tsum;
    __syncthreads();
    for (int off = 1; off < 256; off <<= 1) {
        const int u = (t >= off) ? sh[t - off] : 0;
        __syncthreads();
        sh[t] += u;
        __syncthreads();
    }
    const int texcl = sh[t] - tsum + boff[blockIdx.x];
    if (i0 < N_NODES) row_ptr[i0] = texcl;
    if (i0 + 1 < N_NODES) row_ptr[i0 + 1] = texcl + d0;
}

// ---------- Phase C: CSR fill, rank via LDS atomics only ----------
__global__ __launch_bounds__(1024) void fill2_kernel(const int* __restrict__ src,
                                                     const int* __restrict__ dst,
                                                     const unsigned char* __restrict__ H,
                                                     const int* __restrict__ row_ptr,
                                                     int* __restrict__ col) {
    __shared__ unsigned int bins[NWORDS];  // 100 KB rank counters
    for (int i = threadIdx.x; i < NWORDS; i += 1024) bins[i] = 0;
    __syncthreads();
    const int b = blockIdx.x;
    const int e0 = b * CHUNK;
    const unsigned char* Hb = H + (size_t)b * N_NODES;
    for (int i = threadIdx.x; i < CHUNK; i += 1024) {
        const int e = e0 + i;
        const int d = dst[e];
        const unsigned int sh = (d & 3) * 8;
        const unsigned int old = atomicAdd(&bins[d >> 2], 1u << sh);
        const int lrank = (old >> sh) & 0xFF;
        const int pos = row_ptr[d] + (int)Hb[d] + lrank;
        col[pos] = src[e];
    }
}

// ---------- Kernel 5: gather-aggregate (bf16, dwordx4 gathers, 4 rows/wave-step) ----------
__global__ __launch_bounds__(256) void aggregate_kernel(
    const ushort* __restrict__ sup,
    const int* __restrict__ row_ptr,
    const int* __restrict__ col,
    const float* __restrict__ b,
    float* __restrict__ out) {
    const int wid = threadIdx.x >> 6;
    const int lane = threadIdx.x & 63;
    const int node = blockIdx.x * 4 + wid;
    if (node >= N_NODES) return;

    const int rs = lane >> 4;   // row slot 0..3
    const int fq = lane & 15;   // feature quad

    const int beg = row_ptr[node];
    const int end = row_ptr[node + 1];

    const uint4* sp = (const uint4*)sup;

    float acc[8] = {};
    for (int base = beg; base < end; base += 64) {
        const int m = min(64, end - base);
        const int mycol = (lane < m) ? col[base + lane] : 0;
        for (int j = 0; j < m; j += 4) {
            const int idx = j + rs;
            const int s = __shfl(mycol, idx < m ? idx : 0);
            if (idx < m) {
                const uint4 v = sp[(long long)s * 16 + fq];
                acc[0] += blo(v.x); acc[1] += bhi(v.x);
                acc[2] += blo(v.y); acc[3] += bhi(v.y);
                acc[4] += blo(v.z); acc[5] += bhi(v.z);
                acc[6] += blo(v.w); acc[7] += bhi(v.w);
            }
        }
    }
#pragma unroll
    for (int i = 0; i < 8; ++i) {
        acc[i] += __shfl_xor(acc[i], 16);
        acc[i] += __shfl_xor(acc[i], 32);
    }
    {
        const uint4 v = sp[(long long)node * 16 + fq];
        acc[0] += blo(v.x); acc[1] += bhi(v.x);
        acc[2] += blo(v.y); acc[3] += bhi(v.y);
        acc[4] += blo(v.z); acc[5] += bhi(v.z);
        acc[6] += blo(v.w); acc[7] += bhi(v.w);
    }
    const float inv = 1.0f / (float)(end - beg + 1);
    const float4 b0 = ((const float4*)b)[fq * 2];
    const float4 b1 = ((const float4*)b)[fq * 2 + 1];
    if (rs == 0) {
        float4 r0, r1;
        r0.x = acc[0] * inv + b0.x; r0.y = acc[1] * inv + b0.y;
        r0.z = acc[2] * inv + b0.z; r0.w = acc[3] * inv + b0.w;
        r1.x = acc[4] * inv + b1.x; r1.y = acc[5] * inv + b1.y;
        r1.z = acc[6] * inv + b1.z; r1.w = acc[7] * inv + b1.w;
        float4* o4 = (float4*)out;
        o4[(long long)node * 32 + fq * 2] = r0;
        o4[(long long)node * 32 + fq * 2 + 1] = r1;
    }
}

extern "C" void kernel_launch(void* const* d_in, const int* in_sizes, int n_in,
                              void* d_out, int out_size, void* d_ws, size_t ws_size,
                              hipStream_t stream) {
    const float* x = (const float*)d_in[0];
    const int* src = (const int*)d_in[1];
    const int* dst = (const int*)d_in[2];
    const float* w = (const float*)d_in[3];
    const float* b = (const float*)d_in[4];
    float* out = (float*)d_out;

    // Workspace: sup 25.6MB | deg .4MB | row_ptr .4MB | col 6.4MB | H 25.6MB | bsum/boff
    char* p = (char*)d_ws;
    ushort* sup = (ushort*)p;    p += ((size_t)N_NODES * F * sizeof(ushort) + 15) & ~15ULL;
    int* deg = (int*)p;          p += ((size_t)N_NODES * sizeof(int) + 15) & ~15ULL;
    int* row_ptr = (int*)p;      p += (((size_t)N_NODES + 1) * sizeof(int) + 15) & ~15ULL;
    int* col = (int*)p;          p += ((size_t)NE * sizeof(int) + 15) & ~15ULL;
    unsigned char* H = (unsigned char*)p;  p += ((size_t)NB * N_NODES + 15) & ~15ULL;
    int* bsum = (int*)p;         p += ((size_t)SCAN_BLOCKS * sizeof(int) + 15) & ~15ULL;
    int* boff = (int*)p;

    gemm_mfma<<<(N_NODES + 127) / 128, 256, 0, stream>>>(x, w, sup);
    chunk_hist<<<NB, 1024, 0, stream>>>(dst, H);
    chunk_scan<<<(N_NODES + 255) / 256, 256, 0, stream>>>(H, deg);
    scan_partial<<<SCAN_BLOCKS, 256, 0, stream>>>(deg, bsum);
    scan_bsum<<<1, 256, 0, stream>>>(bsum, boff, row_ptr);
    scan_apply<<<SCAN_BLOCKS, 256, 0, stream>>>(deg, boff, row_ptr);
    fill2_kernel<<<NB, 1024, 0, stream>>>(src, dst, H, row_ptr, col);
    aggregate_kernel<<<(N_NODES + 3) / 4, 256, 0, stream>>>(sup, row_ptr, col, b, out);
}

// Round 9
// 153.407 us; speedup vs baseline: 2.2959x; 1.0591x over previous
//
#include <hip/hip_runtime.h>

#define N_NODES 100000
#define F 128
#define NE 1600000
#define NB 256
#define CHUNK (NE / NB)          // 6250
#define NWORDS (N_NODES / 4)     // 25000 packed byte-counters
#define SCAN_CHUNK 512
#define SCAN_BLOCKS ((N_NODES + SCAN_CHUNK - 1) / SCAN_CHUNK)  // 196

typedef __attribute__((ext_vector_type(8))) short bf16x8;
typedef __attribute__((ext_vector_type(4))) float f32x4;

// fp32 -> bf16 round-to-nearest-even
__device__ __forceinline__ unsigned short f2bf(float f) {
    unsigned int u = __float_as_uint(f);
    return (unsigned short)((u + 0x7FFFu + ((u >> 16) & 1u)) >> 16);
}
__device__ __forceinline__ float blo(unsigned int v) { return __uint_as_float(v << 16); }
__device__ __forceinline__ float bhi(unsigned int v) { return __uint_as_float(v & 0xFFFF0000u); }

// ---------- Kernel 1: support(bf16) = x @ W via MFMA. 128x128 tile, 4 waves ----------
__global__ __launch_bounds__(256) void gemm_mfma(const float* __restrict__ x,
                                                 const float* __restrict__ w,
                                                 ushort* __restrict__ sup) {
    __shared__ ushort xs[128 * 128];   // 32 KB  [m][k]
    __shared__ ushort wt[128 * 128];   // 32 KB  [n][k]  (W transposed)
    const int t = threadIdx.x;
    const int rbase = blockIdx.x * 128;

#pragma unroll
    for (int it = 0; it < 16; ++it) {
        const int f = it * 256 + t;
        const int c = f & 127;
        const int kq = f >> 7;
        ushort4 o;
        o.x = f2bf(w[(4 * kq + 0) * F + c]);
        o.y = f2bf(w[(4 * kq + 1) * F + c]);
        o.z = f2bf(w[(4 * kq + 2) * F + c]);
        o.w = f2bf(w[(4 * kq + 3) * F + c]);
        ((ushort4*)wt)[c * 32 + (kq ^ ((c & 15) << 1))] = o;
    }
#pragma unroll
    for (int it = 0; it < 16; ++it) {
        const int f = it * 256 + t;
        const int r = f >> 5;
        const int cg = f & 31;
        const int gr = rbase + r;
        float4 v = make_float4(0.f, 0.f, 0.f, 0.f);
        if (gr < N_NODES) v = ((const float4*)x)[(long long)gr * 32 + cg];
        ushort4 o;
        o.x = f2bf(v.x); o.y = f2bf(v.y); o.z = f2bf(v.z); o.w = f2bf(v.w);
        ((ushort4*)xs)[r * 32 + (cg ^ ((r & 15) << 1))] = o;
    }
    __syncthreads();

    const int wid = t >> 6;
    const int lane = t & 63;
    const int wr = wid >> 1;
    const int wc = wid & 1;
    const int l16 = lane & 15;
    const int kg = lane >> 4;

    f32x4 acc[4][4] = {};
    const bf16x8* xs8 = (const bf16x8*)xs;
    const bf16x8* wt8 = (const bf16x8*)wt;

#pragma unroll
    for (int ks = 0; ks < 4; ++ks) {
        const int k8 = ks * 4 + kg;
        bf16x8 a[4], bb[4];
#pragma unroll
        for (int mi = 0; mi < 4; ++mi) {
            const int r = wr * 64 + mi * 16 + l16;
            a[mi] = xs8[r * 16 + (k8 ^ (r & 15))];
        }
#pragma unroll
        for (int ni = 0; ni < 4; ++ni) {
            const int c = wc * 64 + ni * 16 + l16;
            bb[ni] = wt8[c * 16 + (k8 ^ (c & 15))];
        }
#pragma unroll
        for (int mi = 0; mi < 4; ++mi)
#pragma unroll
            for (int ni = 0; ni < 4; ++ni)
                acc[mi][ni] = __builtin_amdgcn_mfma_f32_16x16x32_bf16(
                    a[mi], bb[ni], acc[mi][ni], 0, 0, 0);
    }

#pragma unroll
    for (int mi = 0; mi < 4; ++mi) {
#pragma unroll
        for (int reg = 0; reg < 4; ++reg) {
            const int r = rbase + wr * 64 + mi * 16 + kg * 4 + reg;
            if (r < N_NODES) {
#pragma unroll
                for (int ni = 0; ni < 4; ++ni) {
                    const int c = wc * 64 + ni * 16 + l16;
                    sup[(long long)r * F + c] = f2bf(acc[mi][ni][reg]);
                }
            }
        }
    }
}

// ---------- Phase A: per-chunk histogram (LDS byte-packed), dump to H[b][N] ----------
__global__ __launch_bounds__(1024) void chunk_hist(const int* __restrict__ dst,
                                                   unsigned char* __restrict__ H) {
    __shared__ unsigned int bins[NWORDS];  // 100 KB
    for (int i = threadIdx.x; i < NWORDS; i += 1024) bins[i] = 0;
    __syncthreads();
    const int b = blockIdx.x;
    const int e0 = b * CHUNK;
    for (int i = threadIdx.x; i < CHUNK; i += 1024) {
        const int d = dst[e0 + i];
        atomicAdd(&bins[d >> 2], 1u << ((d & 3) * 8));
    }
    __syncthreads();
    uint4* Ho = (uint4*)(H + (size_t)b * N_NODES);
    const uint4* bi = (const uint4*)bins;
    for (int i = threadIdx.x; i < NWORDS / 4; i += 1024) Ho[i] = bi[i];
}

// ---------- Phase B: SWAR scan of H along chunks (1 thread = 1 word = 4 nodes) ----------
__global__ void chunk_scan(unsigned int* __restrict__ Hw, int* __restrict__ deg) {
    const int wd = blockIdx.x * blockDim.x + threadIdx.x;
    if (wd >= NWORDS) return;
    unsigned int run = 0;
    for (int b = 0; b < NB; ++b) {
        unsigned int* p = Hw + (size_t)b * NWORDS + wd;
        const unsigned int t = *p;
        *p = run;
        run += t;  // byte-wise: per-node prefix < 256, no cross-byte carry
    }
    ((int4*)deg)[wd] = make_int4((int)(run & 255u), (int)((run >> 8) & 255u),
                                 (int)((run >> 16) & 255u), (int)(run >> 24));
}

// ---------- Scan kernels: two-level exclusive scan over deg -> row_ptr ----------
__global__ void scan_partial(const int* __restrict__ deg, int* __restrict__ bsum) {
    __shared__ int red[256];
    const int t = threadIdx.x;
    const int base = blockIdx.x * SCAN_CHUNK;
    int s = 0;
    for (int i = t; i < SCAN_CHUNK; i += 256) {
        const int idx = base + i;
        if (idx < N_NODES) s += deg[idx];
    }
    red[t] = s;
    __syncthreads();
    for (int off = 128; off > 0; off >>= 1) {
        if (t < off) red[t] += red[t + off];
        __syncthreads();
    }
    if (t == 0) bsum[blockIdx.x] = red[0];
}

__global__ void scan_bsum(const int* __restrict__ bsum, int* __restrict__ boff,
                          int* __restrict__ row_ptr) {
    __shared__ int sh[256];
    const int t = threadIdx.x;
    const int v = (t < SCAN_BLOCKS) ? bsum[t] : 0;
    sh[t] = v;
    __syncthreads();
    for (int off = 1; off < 256; off <<= 1) {
        const int u = (t >= off) ? sh[t - off] : 0;
        __syncthreads();
        sh[t] += u;
        __syncthreads();
    }
    if (t < SCAN_BLOCKS) boff[t] = sh[t] - v;
    if (t == 0) row_ptr[N_NODES] = NE;
}

__global__ void scan_apply(const int* __restrict__ deg, const int* __restrict__ boff,
                           int* __restrict__ row_ptr) {
    __shared__ int sh[256];
    const int t = threadIdx.x;
    const int base = blockIdx.x * SCAN_CHUNK;
    const int i0 = base + t * 2;
    const int d0 = (i0 < N_NODES) ? deg[i0] : 0;
    const int d1 = (i0 + 1 < N_NODES) ? deg[i0 + 1] : 0;
    const int tsum = d0 + d1;
    sh[t] = tsum;
    __syncthreads();
    for (int off = 1; off < 256; off <<= 1) {
        const int u = (t >= off) ? sh[t - off] : 0;
        __syncthreads();
        sh[t] += u;
        __syncthreads();
    }
    const int texcl = sh[t] - tsum + boff[blockIdx.x];
    if (i0 < N_NODES) row_ptr[i0] = texcl;
    if (i0 + 1 < N_NODES) row_ptr[i0 + 1] = texcl + d0;
}

// ---------- Phase C: CSR fill, rank via LDS atomics only ----------
__global__ __launch_bounds__(1024) void fill2_kernel(const int* __restrict__ src,
                                                     const int* __restrict__ dst,
                                                     const unsigned char* __restrict__ H,
                                                     const int* __restrict__ row_ptr,
                                                     int* __restrict__ col) {
    __shared__ unsigned int bins[NWORDS];  // 100 KB rank counters
    for (int i = threadIdx.x; i < NWORDS; i += 1024) bins[i] = 0;
    __syncthreads();
    const int b = blockIdx.x;
    const int e0 = b * CHUNK;
    const unsigned char* Hb = H + (size_t)b * N_NODES;
    for (int i = threadIdx.x; i < CHUNK; i += 1024) {
        const int e = e0 + i;
        const int d = dst[e];
        const unsigned int sh = (d & 3) * 8;
        const unsigned int old = atomicAdd(&bins[d >> 2], 1u << sh);
        const int lrank = (old >> sh) & 0xFF;
        const int pos = row_ptr[d] + (int)Hb[d] + lrank;
        col[pos] = src[e];
    }
}

// ---------- Kernel 5: gather-aggregate, 4-deep load pipeline ----------
__global__ __launch_bounds__(256) void aggregate_kernel(
    const ushort* __restrict__ sup,
    const int* __restrict__ row_ptr,
    const int* __restrict__ col,
    const float* __restrict__ b,
    float* __restrict__ out) {
    const int wid = threadIdx.x >> 6;
    const int lane = threadIdx.x & 63;
    const int node = blockIdx.x * 4 + wid;
    if (node >= N_NODES) return;

    const int rs = lane >> 4;   // row slot 0..3
    const int fq = lane & 15;   // feature quad

    const int beg = row_ptr[node];
    const int end = row_ptr[node + 1];

    const uint4* sp = (const uint4*)sup;

    float acc[8] = {};
    for (int base = beg; base < end; base += 64) {
        const int m = min(64, end - base);
        const int mycol = (lane < m) ? col[base + lane] : 0;
#pragma unroll
        for (int g = 0; g < 4; ++g) {
            if (g * 16 >= m) break;                 // wave-uniform early exit
            uint4 v[4] = {};                        // zero: bf16 0x0000 == 0.0f
#pragma unroll
            for (int q = 0; q < 4; ++q) {
                const int idx = g * 16 + q * 4 + rs;
                const int s = __shfl(mycol, idx < m ? idx : 0);
                if (idx < m) v[q] = sp[(long long)s * 16 + fq];
            }
#pragma unroll
            for (int q = 0; q < 4; ++q) {
                acc[0] += blo(v[q].x); acc[1] += bhi(v[q].x);
                acc[2] += blo(v[q].y); acc[3] += bhi(v[q].y);
                acc[4] += blo(v[q].z); acc[5] += bhi(v[q].z);
                acc[6] += blo(v[q].w); acc[7] += bhi(v[q].w);
            }
        }
    }
    // reduce across the 4 row slots FIRST...
#pragma unroll
    for (int i = 0; i < 8; ++i) {
        acc[i] += __shfl_xor(acc[i], 16);
        acc[i] += __shfl_xor(acc[i], 32);
    }
    // ...THEN add self-loop exactly once (post-reduction; R8 bug was pre-reduction = 4x count)
    {
        const uint4 v = sp[(long long)node * 16 + fq];
        acc[0] += blo(v.x); acc[1] += bhi(v.x);
        acc[2] += blo(v.y); acc[3] += bhi(v.y);
        acc[4] += blo(v.z); acc[5] += bhi(v.z);
        acc[6] += blo(v.w); acc[7] += bhi(v.w);
    }
    const float inv = 1.0f / (float)(end - beg + 1);
    const float4 b0 = ((const float4*)b)[fq * 2];
    const float4 b1 = ((const float4*)b)[fq * 2 + 1];
    if (rs == 0) {
        float4 r0, r1;
        r0.x = acc[0] * inv + b0.x; r0.y = acc[1] * inv + b0.y;
        r0.z = acc[2] * inv + b0.z; r0.w = acc[3] * inv + b0.w;
        r1.x = acc[4] * inv + b1.x; r1.y = acc[5] * inv + b1.y;
        r1.z = acc[6] * inv + b1.z; r1.w = acc[7] * inv + b1.w;
        float4* o4 = (float4*)out;
        o4[(long long)node * 32 + fq * 2] = r0;
        o4[(long long)node * 32 + fq * 2 + 1] = r1;
    }
}

extern "C" void kernel_launch(void* const* d_in, const int* in_sizes, int n_in,
                              void* d_out, int out_size, void* d_ws, size_t ws_size,
                              hipStream_t stream) {
    const float* x = (const float*)d_in[0];
    const int* src = (const int*)d_in[1];
    const int* dst = (const int*)d_in[2];
    const float* w = (const float*)d_in[3];
    const float* b = (const float*)d_in[4];
    float* out = (float*)d_out;

    // Workspace: sup 25.6MB | deg .4MB | row_ptr .4MB | col 6.4MB | H 25.6MB | bsum/boff
    char* p = (char*)d_ws;
    ushort* sup = (ushort*)p;    p += ((size_t)N_NODES * F * sizeof(ushort) + 15) & ~15ULL;
    int* deg = (int*)p;          p += ((size_t)N_NODES * sizeof(int) + 15) & ~15ULL;
    int* row_ptr = (int*)p;      p += (((size_t)N_NODES + 1) * sizeof(int) + 15) & ~15ULL;
    int* col = (int*)p;          p += ((size_t)NE * sizeof(int) + 15) & ~15ULL;
    unsigned char* H = (unsigned char*)p;  p += ((size_t)NB * N_NODES + 15) & ~15ULL;
    int* bsum = (int*)p;         p += ((size_t)SCAN_BLOCKS * sizeof(int) + 15) & ~15ULL;
    int* boff = (int*)p;

    gemm_mfma<<<(N_NODES + 127) / 128, 256, 0, stream>>>(x, w, sup);
    chunk_hist<<<NB, 1024, 0, stream>>>(dst, H);
    chunk_scan<<<(NWORDS + 255) / 256, 256, 0, stream>>>((unsigned int*)H, deg);
    scan_partial<<<SCAN_BLOCKS, 256, 0, stream>>>(deg, bsum);
    scan_bsum<<<1, 256, 0, stream>>>(bsum, boff, row_ptr);
    scan_apply<<<SCAN_BLOCKS, 256, 0, stream>>>(deg, boff, row_ptr);
    fill2_kernel<<<NB, 1024, 0, stream>>>(src, dst, H, row_ptr, col);
    aggregate_kernel<<<(N_NODES + 3) / 4, 256, 0, stream>>>(sup, row_ptr, col, b, out);
}